// Round 2
// baseline (837.926 us; speedup 1.0000x reference)
//
#include <hip/hip_runtime.h>
#include <hip/hip_cooperative_groups.h>

namespace cg = cooperative_groups;

#define C_CH  128
#define NP    32768
#define K_PWL 20
#define LAT   8
#define HID   8
#define SLOTS 32
#define PTS   4          // points per thread per group (phase 1 / legacy pass1)

__device__ __forceinline__ float fast_tanh(float x) {
    float e = __expf(2.0f * x);
    return fmaf(-2.0f, __builtin_amdgcn_rcpf(e + 1.0f), 1.0f);
}

// monotone float<->uint encoding for atomic min/max on floats (legacy path)
__device__ __forceinline__ unsigned fenc(float f) {
    unsigned u = __float_as_uint(f);
    return (u & 0x80000000u) ? ~u : (u | 0x80000000u);
}
__device__ __forceinline__ float fdec(unsigned e) {
    unsigned u = (e & 0x80000000u) ? (e ^ 0x80000000u) : ~e;
    return __uint_as_float(u);
}

// 8->8(tanh)->1(tanh) MLP; W layout: W1[64], b1[8]@64, W2[8]@72, b2@80.
// Identical op order to the verified kernel -> identical numerics.
__device__ __forceinline__ float mlp_eval(const float* W, float4 r0, float4 r1) {
    float acc = W[80];
    #pragma unroll
    for (int j = 0; j < HID; j++) {
        float hh = W[64 + j];
        hh = fmaf(r0.x, W[0 * 8 + j], hh);
        hh = fmaf(r0.y, W[1 * 8 + j], hh);
        hh = fmaf(r0.z, W[2 * 8 + j], hh);
        hh = fmaf(r0.w, W[3 * 8 + j], hh);
        hh = fmaf(r1.x, W[4 * 8 + j], hh);
        hh = fmaf(r1.y, W[5 * 8 + j], hh);
        hh = fmaf(r1.z, W[6 * 8 + j], hh);
        hh = fmaf(r1.w, W[7 * 8 + j], hh);
        acc = fmaf(fast_tanh(hh), W[72 + j], acc);
    }
    return fast_tanh(acc);
}

// ===================== FUSED COOPERATIVE KERNEL (v2) =======================
// Key change vs v1: phase 1 keeps pass1's CONTIGUOUS per-channel reads and
// writes x/e to a blocked-transpose layout [NP/32][C][32], so phase 2's
// all-channel gather becomes a contiguous 16 KB read. No [C-strided 2KB]
// gather anywhere (that pattern measured 0.47 TB/s in v1 / old pass2).
//
// grid = nblk (= C_CH << chLog, 512 or 1024) blocks x 256 threads.
//   phase 1 : block b -> channel c=b>>chLog, segment q=b&(chPer-1) of
//             NP/chPer points. Contiguous reads, tiled writes, block partials.
//   sync
//   phase 2a: block 0 reduces per-channel min/max (chPer partials each) and
//             global e sums -> gmm / gstat.
//   sync
//   phase 2b: each block finishes 1024/nblk n-tiles: contiguous tile read,
//             PWL + e-standardize, XOR-swizzled LDS transpose, coalesced
//             float4 stores to out[N,C]. yp regenerated per block (register
//             sorting network) by upper 128 threads, overlapped.
__global__ __launch_bounds__(256, 4)
void fused2(const float* __restrict__ zf, const float* __restrict__ zx,
            const float* __restrict__ ze,
            const float* __restrict__ Wx1, const float* __restrict__ bx1,
            const float* __restrict__ Wx2, const float* __restrict__ bx2,
            const float* __restrict__ We1, const float* __restrict__ be1,
            const float* __restrict__ We2, const float* __restrict__ be2,
            const float* __restrict__ Wf1, const float* __restrict__ bf1,
            const float* __restrict__ Wf2, const float* __restrict__ bf2,
            const unsigned char* __restrict__ dirs_raw,
            float* __restrict__ out,
            float* __restrict__ xtile,   // [NP/32][C_CH][32]
            float* __restrict__ etile,   // [NP/32][C_CH][32]
            double* __restrict__ psum,   // [nblk][2]
            float* __restrict__ pminB,   // [nblk]
            float* __restrict__ pmaxB,   // [nblk]
            float* __restrict__ gmm,     // [256] = min[128], max[128]
            float* __restrict__ gstat,   // [2] = mean, 0.1/std
            int chLog, int nblk) {
    __shared__ float sw[162];
    __shared__ float rf[16];
    __shared__ double rsd[8];
    __shared__ float ytile[C_CH * 32];      // XOR-swizzled transpose tile
    __shared__ float syp[C_CH * K_PWL];
    __shared__ float smin[C_CH], sinv[C_CH];
    __shared__ float sstat2[2];
    __shared__ int is_i32;

    int t = threadIdx.x;
    int b = blockIdx.x;
    int w = t >> 6, lane = t & 63;
    cg::grid_group grid = cg::this_grid();

    // ---- stage x/e MLP weights to LDS ----
    if (t < 64)        sw[t] = Wx1[t];
    else if (t < 72)   sw[t] = bx1[t - 64];
    else if (t < 80)   sw[t] = Wx2[t - 72];
    else if (t == 80)  sw[80] = bx2[0];
    else if (t < 145)  sw[t] = We1[t - 81];
    else if (t < 153)  sw[t] = be1[t - 145];
    else if (t < 161)  sw[t] = We2[t - 153];
    else if (t == 161) sw[161] = be2[0];
    __syncthreads();

    // =================== phase 1: MLP, contiguous reads ===================
    int chPer = 1 << chLog;
    int c = b >> chLog;
    int q = b & (chPer - 1);
    int ppb = NP >> chLog;                  // points per block
    int nbase = q * ppb;
    int G = ppb >> 10;                      // groups of 1024 points
    size_t rowz = (size_t)c * NP;
    const float4* zx4 = (const float4*)zx;
    const float4* ze4 = (const float4*)ze;
    int cbase = c * 32;

    float mn = 3.0e38f, mx = -3.0e38f, s = 0.f, s2 = 0.f;
    for (int g = 0; g < G; ++g) {
        int nb0 = nbase + (g << 10) + t;
        float4 ax[PTS][2], ae[PTS][2];
        #pragma unroll
        for (int k = 0; k < PTS; ++k) {
            size_t zi = (rowz + nb0 + (k << 8)) * 2;
            ax[k][0] = zx4[zi]; ax[k][1] = zx4[zi + 1];
            ae[k][0] = ze4[zi]; ae[k][1] = ze4[zi + 1];
        }
        #pragma unroll
        for (int k = 0; k < PTS; ++k) {
            float xv = mlp_eval(sw, ax[k][0], ax[k][1]);
            float ev = mlp_eval(sw + 81, ae[k][0], ae[k][1]);
            int n = nb0 + (k << 8);
            int addr = (n >> 5) * (C_CH * 32) + cbase + (n & 31);
            xtile[addr] = xv;
            etile[addr] = ev;
            mn = fminf(mn, xv); mx = fmaxf(mx, xv);
            s += ev; s2 = fmaf(ev, ev, s2);
        }
    }
    #pragma unroll
    for (int o = 32; o > 0; o >>= 1) {
        mn = fminf(mn, __shfl_down(mn, o));
        mx = fmaxf(mx, __shfl_down(mx, o));
        s += __shfl_down(s, o);
        s2 += __shfl_down(s2, o);
    }
    if (lane == 0) { rf[w] = mn; rf[4 + w] = mx; rf[8 + w] = s; rf[12 + w] = s2; }
    __syncthreads();
    if (t == 0) {
        mn = fminf(fminf(rf[0], rf[1]), fminf(rf[2], rf[3]));
        mx = fmaxf(fmaxf(rf[4], rf[5]), fmaxf(rf[6], rf[7]));
        pminB[b] = mn; pmaxB[b] = mx;
        psum[2 * b]     = (double)rf[8]  + (double)rf[9]  + (double)rf[10] + (double)rf[11];
        psum[2 * b + 1] = (double)rf[12] + (double)rf[13] + (double)rf[14] + (double)rf[15];
    }
    __threadfence();
    grid.sync();

    // =================== phase 2a: global reductions (block 0) ============
    if (b == 0) {
        if (t < C_CH) {
            const volatile float* vmin = pminB;
            const volatile float* vmax = pmaxB;
            float m1 = 3.0e38f, m2 = -3.0e38f;
            for (int qq = 0; qq < chPer; ++qq) {
                m1 = fminf(m1, vmin[(t << chLog) + qq]);
                m2 = fmaxf(m2, vmax[(t << chLog) + qq]);
            }
            gmm[t] = m1; gmm[C_CH + t] = m2;
        }
        const volatile double* vs = psum;
        double S = 0.0, S2 = 0.0;
        for (int i = t; i < nblk; i += 256) {
            S += vs[2 * i]; S2 += vs[2 * i + 1];
        }
        #pragma unroll
        for (int o = 32; o > 0; o >>= 1) {
            S  += __shfl_down(S, o);
            S2 += __shfl_down(S2, o);
        }
        if (lane == 0) { rsd[w] = S; rsd[4 + w] = S2; }
        __syncthreads();
        if (t == 0) {
            S  = rsd[0] + rsd[1] + rsd[2] + rsd[3];
            S2 = rsd[4] + rsd[5] + rsd[6] + rsd[7];
            double M = (double)C_CH * NP;
            double mean = S / M;
            double var = (S2 - S * S / M) / (M - 1.0);
            gstat[0] = (float)mean;
            gstat[1] = (float)(0.1 / sqrt(var));
        }
        __threadfence();
    }
    grid.sync();

    // =================== phase 2b: finish + transpose + store =============
    if (t == 0) {
        const int* di = (const int*)dirs_raw;     // bool storage sniff
        int ok = 1;
        for (int i = 0; i < 32; i++) { int v = di[i]; if (v != 0 && v != 1) ok = 0; }
        is_i32 = ok;
        const volatile float* gs = gstat;
        sstat2[0] = gs[0]; sstat2[1] = gs[1];
    }
    if (t < C_CH) {
        const volatile float* g = gmm;
        float m1 = g[t], m2 = g[C_CH + t];
        smin[t] = m1;
        sinv[t] = __builtin_amdgcn_rcpf(m2 - m1);
    }
    __syncthreads();          // is_i32 ready for upper threads
    if (t >= C_CH) {
        // redundant per-block yp generation (register sorting network)
        int cc = t - C_CH;
        float z[LAT];
        #pragma unroll
        for (int l = 0; l < LAT; l++) z[l] = zf[cc * LAT + l];
        float h[HID];
        #pragma unroll
        for (int j = 0; j < HID; j++) {
            float a = bf1[j];
            #pragma unroll
            for (int l = 0; l < LAT; l++) a = fmaf(z[l], Wf1[l * HID + j], a);
            h[j] = fast_tanh(a);
        }
        float p[K_PWL];
        #pragma unroll
        for (int k = 0; k < K_PWL; k++) {
            float a = bf2[k];
            #pragma unroll
            for (int j = 0; j < HID; j++) a = fmaf(h[j], Wf2[j * K_PWL + k], a);
            p[k] = fast_tanh(a);
        }
        #pragma unroll
        for (int ph = 0; ph < K_PWL; ph++) {
            #pragma unroll
            for (int k = (ph & 1); k + 1 < K_PWL; k += 2) {
                float lo = fminf(p[k], p[k + 1]);
                float hi = fmaxf(p[k], p[k + 1]);
                p[k] = lo; p[k + 1] = hi;
            }
        }
        int dir = is_i32 ? (((const int*)dirs_raw)[cc] != 0) : (dirs_raw[cc] != 0);
        #pragma unroll
        for (int k = 0; k < K_PWL; k++)
            syp[cc * K_PWL + k] = dir ? p[k] : p[K_PWL - 1 - k];
    }
    __syncthreads();

    const float INV_DENOM = 1.0f / (1.0f / 19.0f + 1e-7f);
    float mean = sstat2[0], escale = sstat2[1];
    int tpb = (NP / 32) / nblk;               // 1 or 2 tiles per block

    for (int T = b * tpb; T < b * tpb + tpb; ++T) {
        const float4* xt4 = (const float4*)(xtile + (size_t)T * (C_CH * 32));
        const float4* et4 = (const float4*)(etile + (size_t)T * (C_CH * 32));
        #pragma unroll
        for (int i = 0; i < 4; ++i) {
            int fi = i * 256 + t;             // float4 index within tile
            float4 xv = xt4[fi];
            float4 ev = et4[fi];
            int cc = fi >> 3;                 // 8 float4 per channel row
            int j0 = (fi & 7) * 4;
            float sm = smin[cc], si = sinv[cc];
            int sb = cc * K_PWL;
            int cb = cc * 32, cx = cc & 31;
            // manual component unroll (static indexing only)
            {
                float xn = (xv.x - sm) * si;
                int seg = (int)floorf(xn * 19.0f); seg = max(0, min(18, seg));
                float y0 = syp[sb + seg], y1 = syp[sb + seg + 1];
                float y = fmaf((xn - (float)seg * (1.0f / 19.0f)) * INV_DENOM, y1 - y0, y0);
                ytile[cb + ((j0 + 0) ^ cx)] = fmaf(ev.x - mean, escale, y);
            }
            {
                float xn = (xv.y - sm) * si;
                int seg = (int)floorf(xn * 19.0f); seg = max(0, min(18, seg));
                float y0 = syp[sb + seg], y1 = syp[sb + seg + 1];
                float y = fmaf((xn - (float)seg * (1.0f / 19.0f)) * INV_DENOM, y1 - y0, y0);
                ytile[cb + ((j0 + 1) ^ cx)] = fmaf(ev.y - mean, escale, y);
            }
            {
                float xn = (xv.z - sm) * si;
                int seg = (int)floorf(xn * 19.0f); seg = max(0, min(18, seg));
                float y0 = syp[sb + seg], y1 = syp[sb + seg + 1];
                float y = fmaf((xn - (float)seg * (1.0f / 19.0f)) * INV_DENOM, y1 - y0, y0);
                ytile[cb + ((j0 + 2) ^ cx)] = fmaf(ev.z - mean, escale, y);
            }
            {
                float xn = (xv.w - sm) * si;
                int seg = (int)floorf(xn * 19.0f); seg = max(0, min(18, seg));
                float y0 = syp[sb + seg], y1 = syp[sb + seg + 1];
                float y = fmaf((xn - (float)seg * (1.0f / 19.0f)) * INV_DENOM, y1 - y0, y0);
                ytile[cb + ((j0 + 3) ^ cx)] = fmaf(ev.w - mean, escale, y);
            }
        }
        __syncthreads();
        #pragma unroll
        for (int i = 0; i < 4; ++i) {
            int fi = i * 256 + t;
            int j = fi >> 5;                  // row within tile (0..31)
            int c4 = (fi & 31) * 4;           // channel group
            float4 o;
            o.x = ytile[(c4 + 0) * 32 + (j ^ ((c4 + 0) & 31))];
            o.y = ytile[(c4 + 1) * 32 + (j ^ ((c4 + 1) & 31))];
            o.z = ytile[(c4 + 2) * 32 + (j ^ ((c4 + 2) & 31))];
            o.w = ytile[(c4 + 3) * 32 + (j ^ ((c4 + 3) & 31))];
            ((float4*)out)[(((size_t)(T * 32 + j)) * C_CH + c4) >> 2] = o;
        }
        if (T + 1 < b * tpb + tpb) __syncthreads();
    }
}

// ============================ LEGACY FALLBACK PATH =========================
__global__ void prep(const float* __restrict__ zf,
                     const float* __restrict__ Wf1, const float* __restrict__ bf1,
                     const float* __restrict__ Wf2, const float* __restrict__ bf2,
                     const unsigned char* __restrict__ dirs_raw,
                     float* __restrict__ ypw,
                     unsigned* cminE, unsigned* cmaxE, double* sums) {
    int t = threadIdx.x;
    if (t < C_CH) { cminE[t] = 0xFFFFFFFFu; cmaxE[t] = 0u; }
    if (t < 2 * SLOTS) sums[t] = 0.0;

    __shared__ int is_i32;
    if (t == 0) {
        const int* di = (const int*)dirs_raw;
        int ok = 1;
        for (int i = 0; i < 32; i++) { int v = di[i]; if (v != 0 && v != 1) ok = 0; }
        is_i32 = ok;
    }
    __syncthreads();
    if (t >= C_CH) return;
    int c = t;

    float z[LAT];
    #pragma unroll
    for (int l = 0; l < LAT; l++) z[l] = zf[c * LAT + l];
    float h[HID];
    #pragma unroll
    for (int j = 0; j < HID; j++) {
        float a = bf1[j];
        #pragma unroll
        for (int l = 0; l < LAT; l++) a = fmaf(z[l], Wf1[l * HID + j], a);
        h[j] = fast_tanh(a);
    }
    float p[K_PWL];
    #pragma unroll
    for (int k = 0; k < K_PWL; k++) {
        float a = bf2[k];
        #pragma unroll
        for (int j = 0; j < HID; j++) a = fmaf(h[j], Wf2[j * K_PWL + k], a);
        p[k] = fast_tanh(a);
    }
    for (int i = 1; i < K_PWL; i++) {
        float key = p[i];
        int j = i - 1;
        while (j >= 0 && p[j] > key) { p[j + 1] = p[j]; j--; }
        p[j + 1] = key;
    }
    int dir = is_i32 ? (((const int*)dirs_raw)[c] != 0) : (dirs_raw[c] != 0);
    for (int k = 0; k < K_PWL; k++)
        ypw[c * K_PWL + k] = dir ? p[k] : p[K_PWL - 1 - k];
}

__global__ __launch_bounds__(256)
void pass1(const float* __restrict__ zx, const float* __restrict__ ze,
           const float* __restrict__ Wx1, const float* __restrict__ bx1,
           const float* __restrict__ Wx2, const float* __restrict__ bx2,
           const float* __restrict__ We1, const float* __restrict__ be1,
           const float* __restrict__ We2, const float* __restrict__ be2,
           float* __restrict__ xraw, float* __restrict__ eraw,
           unsigned* __restrict__ cminE, unsigned* __restrict__ cmaxE,
           double* __restrict__ sums) {
    __shared__ float sw[162];
    int t = threadIdx.x;
    if (t < 64)       sw[t] = Wx1[t];
    else if (t < 72)  sw[t] = bx1[t - 64];
    else if (t < 80)  sw[t] = Wx2[t - 72];
    else if (t == 80) sw[80] = bx2[0];
    else if (t < 145) sw[t] = We1[t - 81];
    else if (t < 153) sw[t] = be1[t - 145];
    else if (t < 161) sw[t] = We2[t - 153];
    else if (t == 161) sw[161] = be2[0];
    __syncthreads();

    int c = blockIdx.y;
    int n0 = blockIdx.x * (256 * PTS) + t;
    size_t row = (size_t)c * NP;
    const float4* zx4 = (const float4*)(zx + row * LAT);
    const float4* ze4 = (const float4*)(ze + row * LAT);

    float4 ax[PTS][2], ae[PTS][2];
    #pragma unroll
    for (int k = 0; k < PTS; k++) {
        int n = n0 + k * 256;
        ax[k][0] = zx4[2 * n];  ax[k][1] = zx4[2 * n + 1];
        ae[k][0] = ze4[2 * n];  ae[k][1] = ze4[2 * n + 1];
    }

    float xv[PTS], ev[PTS];
    #pragma unroll
    for (int k = 0; k < PTS; k++) xv[k] = mlp_eval(sw, ax[k][0], ax[k][1]);
    #pragma unroll
    for (int k = 0; k < PTS; k++) ev[k] = mlp_eval(sw + 81, ae[k][0], ae[k][1]);

    float mn = xv[0], mx = xv[0], s = 0.f, s2 = 0.f;
    #pragma unroll
    for (int k = 0; k < PTS; k++) {
        xraw[row + n0 + k * 256] = xv[k];
        eraw[row + n0 + k * 256] = ev[k];
        mn = fminf(mn, xv[k]); mx = fmaxf(mx, xv[k]);
        s += ev[k]; s2 += ev[k] * ev[k];
    }

    #pragma unroll
    for (int o = 32; o > 0; o >>= 1) {
        mn = fminf(mn, __shfl_down(mn, o));
        mx = fmaxf(mx, __shfl_down(mx, o));
        s += __shfl_down(s, o);
        s2 += __shfl_down(s2, o);
    }
    __shared__ float rmn[4], rmx[4], rs[4], rs2[4];
    int wave = t >> 6, lane = t & 63;
    if (lane == 0) { rmn[wave] = mn; rmx[wave] = mx; rs[wave] = s; rs2[wave] = s2; }
    __syncthreads();
    if (t == 0) {
        for (int w = 1; w < 4; w++) {
            mn = fminf(mn, rmn[w]); mx = fmaxf(mx, rmx[w]);
            s += rs[w]; s2 += rs2[w];
        }
        atomicMin(&cminE[c], fenc(mn));
        atomicMax(&cmaxE[c], fenc(mx));
        int slot = (blockIdx.x + blockIdx.y) & (SLOTS - 1);
        atomicAdd(&sums[2 * slot], (double)s);
        atomicAdd(&sums[2 * slot + 1], (double)s2);
    }
}

__global__ __launch_bounds__(256)
void pass2(const float* __restrict__ xraw, const float* __restrict__ eraw,
           const float* __restrict__ ypw,
           const unsigned* __restrict__ cminE, const unsigned* __restrict__ cmaxE,
           const double* __restrict__ sums,
           float* __restrict__ out) {
    __shared__ float ytile[C_CH * 33];
    __shared__ float syp[C_CH * K_PWL];
    __shared__ float smin[C_CH], sinv[C_CH];
    __shared__ float sstat[2];

    int t = threadIdx.x;
    for (int i = t; i < C_CH * K_PWL; i += 256) syp[i] = ypw[i];
    if (t < C_CH) {
        float mn = fdec(cminE[t]);
        float mx = fdec(cmaxE[t]);
        smin[t] = mn;
        sinv[t] = __builtin_amdgcn_rcpf(mx - mn);
    }
    if (t == 0) {
        double s = 0.0, s2 = 0.0;
        for (int i = 0; i < SLOTS; i++) { s += sums[2 * i]; s2 += sums[2 * i + 1]; }
        double M = (double)C_CH * NP;
        double mean = s / M;
        double var = (s2 - s * s / M) / (M - 1.0);
        sstat[0] = (float)mean;
        sstat[1] = (float)(0.1 / sqrt(var));
    }
    __syncthreads();

    const float INV_DENOM = 1.0f / (1.0f / 19.0f + 1e-7f);
    float mean = sstat[0], escale = sstat[1];
    int n0 = blockIdx.x * 32;

    #pragma unroll
    for (int i = 0; i < 16; i++) {
        int idx = i * 256 + t;
        int c = idx >> 5;
        int j = idx & 31;
        size_t g = (size_t)c * NP + (n0 + j);
        float x = xraw[g];
        float e = eraw[g];
        float xn = (x - smin[c]) * sinv[c];
        int seg = (int)floorf(xn * 19.0f);
        seg = max(0, min(18, seg));
        float y0 = syp[c * K_PWL + seg];
        float y1 = syp[c * K_PWL + seg + 1];
        float y = fmaf((xn - (float)seg * (1.0f / 19.0f)) * INV_DENOM, y1 - y0, y0);
        y = fmaf(e - mean, escale, y);
        ytile[c * 33 + j] = y;
    }
    __syncthreads();
    #pragma unroll
    for (int i = 0; i < 16; i++) {
        int idx = i * 256 + t;
        int j = idx >> 7;
        int c = idx & 127;
        out[(size_t)(n0 + j) * C_CH + c] = ytile[c * 33 + j];
    }
}

extern "C" void kernel_launch(void* const* d_in, const int* in_sizes, int n_in,
                              void* d_out, int out_size, void* d_ws, size_t ws_size,
                              hipStream_t stream) {
    const float* zf  = (const float*)d_in[0];
    const float* zx  = (const float*)d_in[1];
    const float* ze  = (const float*)d_in[2];
    const float* Wx1 = (const float*)d_in[3];
    const float* bx1 = (const float*)d_in[4];
    const float* Wx2 = (const float*)d_in[5];
    const float* bx2 = (const float*)d_in[6];
    const float* We1 = (const float*)d_in[7];
    const float* be1 = (const float*)d_in[8];
    const float* We2 = (const float*)d_in[9];
    const float* be2 = (const float*)d_in[10];
    const float* Wf1 = (const float*)d_in[11];
    const float* bf1 = (const float*)d_in[12];
    const float* Wf2 = (const float*)d_in[13];
    const float* bf2 = (const float*)d_in[14];
    const unsigned char* dirs = (const unsigned char*)d_in[15];
    float* outp = (float*)d_out;

    // mode: 2 = 1024 blocks (4/CU), 1 = 512 blocks (2/CU), 0 = legacy
    static int mode = -1;
    if (mode < 0) {
        int dev = 0, coop = 0, nb = 0, mpc = 0;
        hipGetDevice(&dev);
        hipDeviceGetAttribute(&coop, hipDeviceAttributeCooperativeLaunch, dev);
        hipDeviceGetAttribute(&mpc, hipDeviceAttributeMultiprocessorCount, dev);
        hipError_t oe = hipOccupancyMaxActiveBlocksPerMultiprocessor(
            &nb, reinterpret_cast<const void*>(fused2), 256, 0);
        mode = 0;
        if (coop && oe == hipSuccess && mpc > 0) {
            long cap = (long)nb * mpc;
            if (cap >= 1024) mode = 2;
            else if (cap >= 512) mode = 1;
        }
    }

    size_t need = (size_t)2 * C_CH * NP * 4 + 2 * 1024 * 8 + (2 * 1024 + 256 + 2) * 4;
    if (mode >= 1 && ws_size >= need) {
        float*  xtile = (float*)d_ws;                     // 16 MB
        float*  etile = xtile + (size_t)C_CH * NP;        // 16 MB
        double* psum  = (double*)(etile + (size_t)C_CH * NP);
        float*  pminB = (float*)(psum + 2 * 1024);
        float*  pmaxB = pminB + 1024;
        float*  gmm   = pmaxB + 1024;
        float*  gstat = gmm + 256;
        int nblk  = (mode == 2) ? 1024 : 512;
        int chLog = (mode == 2) ? 3 : 2;
        void* args[] = {
            (void*)&zf,  (void*)&zx,  (void*)&ze,
            (void*)&Wx1, (void*)&bx1, (void*)&Wx2, (void*)&bx2,
            (void*)&We1, (void*)&be1, (void*)&We2, (void*)&be2,
            (void*)&Wf1, (void*)&bf1, (void*)&Wf2, (void*)&bf2,
            (void*)&dirs, (void*)&outp,
            (void*)&xtile, (void*)&etile, (void*)&psum,
            (void*)&pminB, (void*)&pmaxB, (void*)&gmm, (void*)&gstat,
            (void*)&chLog, (void*)&nblk
        };
        hipError_t le = hipLaunchCooperativeKernel(
            reinterpret_cast<const void*>(fused2), dim3(nblk), dim3(256),
            args, 0, stream);
        if (le == hipSuccess) return;
        mode = 0;   // cooperative launch rejected -> permanent legacy fallback
    }

    // legacy 3-kernel path (verified baseline)
    float* xraw = (float*)d_ws;
    float* eraw = xraw + (size_t)C_CH * NP;
    float* ypw  = eraw + (size_t)C_CH * NP;
    unsigned* cminE = (unsigned*)(ypw + C_CH * K_PWL);
    unsigned* cmaxE = cminE + C_CH;
    double* sums = (double*)(cmaxE + C_CH);

    hipLaunchKernelGGL(prep, dim3(1), dim3(256), 0, stream,
                       zf, Wf1, bf1, Wf2, bf2, dirs, ypw, cminE, cmaxE, sums);
    hipLaunchKernelGGL(pass1, dim3(NP / (256 * PTS), C_CH), dim3(256), 0, stream,
                       zx, ze, Wx1, bx1, Wx2, bx2, We1, be1, We2, be2,
                       xraw, eraw, cminE, cmaxE, sums);
    hipLaunchKernelGGL(pass2, dim3(NP / 32), dim3(256), 0, stream,
                       xraw, eraw, ypw, cminE, cmaxE, sums, outp);
}

// Round 3
// 416.637 us; speedup vs baseline: 2.0112x; 2.0112x over previous
//
#include <hip/hip_runtime.h>

#define C_CH  128
#define NP    32768
#define K_PWL 20
#define LAT   8
#define HID   8
#define SLOTS 32
#define P1PTS 2          // points per thread in pass1t (keeps VGPR <= 64)

__device__ __forceinline__ float fast_tanh(float x) {
    float e = __expf(2.0f * x);
    return fmaf(-2.0f, __builtin_amdgcn_rcpf(e + 1.0f), 1.0f);
}

// monotone float<->uint encoding for atomic min/max on floats
__device__ __forceinline__ unsigned fenc(float f) {
    unsigned u = __float_as_uint(f);
    return (u & 0x80000000u) ? ~u : (u | 0x80000000u);
}
__device__ __forceinline__ float fdec(unsigned e) {
    unsigned u = (e & 0x80000000u) ? (e ^ 0x80000000u) : ~e;
    return __uint_as_float(u);
}

// 8->8(tanh)->1(tanh) MLP; W layout: W1[64], b1[8]@64, W2[8]@72, b2@80.
// Identical op order to the verified kernel -> identical numerics.
__device__ __forceinline__ float mlp_eval(const float* W, float4 r0, float4 r1) {
    float acc = W[80];
    #pragma unroll
    for (int j = 0; j < HID; j++) {
        float hh = W[64 + j];
        hh = fmaf(r0.x, W[0 * 8 + j], hh);
        hh = fmaf(r0.y, W[1 * 8 + j], hh);
        hh = fmaf(r0.z, W[2 * 8 + j], hh);
        hh = fmaf(r0.w, W[3 * 8 + j], hh);
        hh = fmaf(r1.x, W[4 * 8 + j], hh);
        hh = fmaf(r1.y, W[5 * 8 + j], hh);
        hh = fmaf(r1.z, W[6 * 8 + j], hh);
        hh = fmaf(r1.w, W[7 * 8 + j], hh);
        acc = fmaf(fast_tanh(hh), W[72 + j], acc);
    }
    return fast_tanh(acc);
}

// one launch: init stats + per-channel yp generation (128 channels, 1 block)
__global__ void prep(const float* __restrict__ zf,
                     const float* __restrict__ Wf1, const float* __restrict__ bf1,
                     const float* __restrict__ Wf2, const float* __restrict__ bf2,
                     const unsigned char* __restrict__ dirs_raw,
                     float* __restrict__ ypw,
                     unsigned* cminE, unsigned* cmaxE, double* sums) {
    int t = threadIdx.x;
    if (t < C_CH) { cminE[t] = 0xFFFFFFFFu; cmaxE[t] = 0u; }
    if (t < 2 * SLOTS) sums[t] = 0.0;

    __shared__ int is_i32;
    if (t == 0) {
        // detect bool storage: int32 words (all 0/1) vs uint8 bytes
        const int* di = (const int*)dirs_raw;
        int ok = 1;
        for (int i = 0; i < 32; i++) { int v = di[i]; if (v != 0 && v != 1) ok = 0; }
        is_i32 = ok;
    }
    __syncthreads();
    if (t >= C_CH) return;
    int c = t;

    float z[LAT];
    #pragma unroll
    for (int l = 0; l < LAT; l++) z[l] = zf[c * LAT + l];
    float h[HID];
    #pragma unroll
    for (int j = 0; j < HID; j++) {
        float a = bf1[j];
        #pragma unroll
        for (int l = 0; l < LAT; l++) a = fmaf(z[l], Wf1[l * HID + j], a);
        h[j] = fast_tanh(a);
    }
    float p[K_PWL];
    #pragma unroll
    for (int k = 0; k < K_PWL; k++) {
        float a = bf2[k];
        #pragma unroll
        for (int j = 0; j < HID; j++) a = fmaf(h[j], Wf2[j * K_PWL + k], a);
        p[k] = fast_tanh(a);
    }
    // insertion sort ascending (20 elems)
    for (int i = 1; i < K_PWL; i++) {
        float key = p[i];
        int j = i - 1;
        while (j >= 0 && p[j] > key) { p[j + 1] = p[j]; j--; }
        p[j + 1] = key;
    }
    int dir = is_i32 ? (((const int*)dirs_raw)[c] != 0) : (dirs_raw[c] != 0);
    for (int k = 0; k < K_PWL; k++)
        ypw[c * K_PWL + k] = dir ? p[k] : p[K_PWL - 1 - k];
}

// grid: (NP/(256*P1PTS), C). Identical math/reductions to the verified pass1;
// only change: stores go to the blocked-transpose layout [NP/32][C][32] so the
// finishing pass reads contiguously, and P1PTS=2 + launch_bounds(...,8) keeps
// VGPR <= 64 -> 8 waves/SIMD cap (round-0 pass1 at 68 VGPR was capped at 4,
// measured 27% occupancy, latency-bound at VALUBusy 30%).
__global__ __launch_bounds__(256, 8)
void pass1t(const float* __restrict__ zx, const float* __restrict__ ze,
            const float* __restrict__ Wx1, const float* __restrict__ bx1,
            const float* __restrict__ Wx2, const float* __restrict__ bx2,
            const float* __restrict__ We1, const float* __restrict__ be1,
            const float* __restrict__ We2, const float* __restrict__ be2,
            float* __restrict__ xtile, float* __restrict__ etile,
            unsigned* __restrict__ cminE, unsigned* __restrict__ cmaxE,
            double* __restrict__ sums) {
    // weights in LDS: Wx1[64] bx1[8] Wx2[8] bx2[1] We1[64] be1[8] We2[8] be2[1]
    __shared__ float sw[162];
    int t = threadIdx.x;
    if (t < 64)       sw[t] = Wx1[t];
    else if (t < 72)  sw[t] = bx1[t - 64];
    else if (t < 80)  sw[t] = Wx2[t - 72];
    else if (t == 80) sw[80] = bx2[0];
    else if (t < 145) sw[t] = We1[t - 81];
    else if (t < 153) sw[t] = be1[t - 145];
    else if (t < 161) sw[t] = We2[t - 153];
    else if (t == 161) sw[161] = be2[0];
    __syncthreads();

    int c = blockIdx.y;
    int n0 = blockIdx.x * (256 * P1PTS) + t;
    size_t row = (size_t)c * NP;
    const float4* zx4 = (const float4*)(zx + row * LAT);
    const float4* ze4 = (const float4*)(ze + row * LAT);

    float4 ax[P1PTS][2], ae[P1PTS][2];
    #pragma unroll
    for (int k = 0; k < P1PTS; k++) {
        int n = n0 + k * 256;
        ax[k][0] = zx4[2 * n];  ax[k][1] = zx4[2 * n + 1];
        ae[k][0] = ze4[2 * n];  ae[k][1] = ze4[2 * n + 1];
    }

    float xv[P1PTS], ev[P1PTS];
    #pragma unroll
    for (int k = 0; k < P1PTS; k++) xv[k] = mlp_eval(sw, ax[k][0], ax[k][1]);
    #pragma unroll
    for (int k = 0; k < P1PTS; k++) ev[k] = mlp_eval(sw + 81, ae[k][0], ae[k][1]);

    float mn = xv[0], mx = xv[0], s = 0.f, s2 = 0.f;
    int cbase = c * 32;
    #pragma unroll
    for (int k = 0; k < P1PTS; k++) {
        int n = n0 + k * 256;
        int addr = (n >> 5) * (C_CH * 32) + cbase + (n & 31);
        xtile[addr] = xv[k];
        etile[addr] = ev[k];
        mn = fminf(mn, xv[k]); mx = fmaxf(mx, xv[k]);
        s += ev[k]; s2 += ev[k] * ev[k];
    }

    #pragma unroll
    for (int o = 32; o > 0; o >>= 1) {
        mn = fminf(mn, __shfl_down(mn, o));
        mx = fmaxf(mx, __shfl_down(mx, o));
        s += __shfl_down(s, o);
        s2 += __shfl_down(s2, o);
    }
    __shared__ float rmn[4], rmx[4], rs[4], rs2[4];
    int wave = t >> 6, lane = t & 63;
    if (lane == 0) { rmn[wave] = mn; rmx[wave] = mx; rs[wave] = s; rs2[wave] = s2; }
    __syncthreads();
    if (t == 0) {
        for (int w = 1; w < 4; w++) {
            mn = fminf(mn, rmn[w]); mx = fmaxf(mx, rmx[w]);
            s += rs[w]; s2 += rs2[w];
        }
        atomicMin(&cminE[c], fenc(mn));
        atomicMax(&cmaxE[c], fenc(mx));
        int slot = (blockIdx.x + blockIdx.y) & (SLOTS - 1);
        atomicAdd(&sums[2 * slot], (double)s);
        atomicAdd(&sums[2 * slot + 1], (double)s2);
    }
}

// grid: NP/32 blocks. Block T reads tile T of [NP/32][C][32] CONTIGUOUSLY
// (16 KB x + 16 KB e, idx = c*32+j), finishes, transposes via pad-33 LDS
// (legacy-proven conflict-free), stores coalesced [N,C].
__global__ __launch_bounds__(256)
void pass2t(const float* __restrict__ xtile, const float* __restrict__ etile,
            const float* __restrict__ ypw,
            const unsigned* __restrict__ cminE, const unsigned* __restrict__ cmaxE,
            const double* __restrict__ sums,
            float* __restrict__ out) {
    __shared__ float ytile[C_CH * 33];
    __shared__ float syp[C_CH * K_PWL];
    __shared__ float smin[C_CH], sinv[C_CH];
    __shared__ float sstat[2];   // mean, 0.1/std

    int t = threadIdx.x;
    for (int i = t; i < C_CH * K_PWL; i += 256) syp[i] = ypw[i];
    if (t < C_CH) {
        float mn = fdec(cminE[t]);
        float mx = fdec(cmaxE[t]);
        smin[t] = mn;
        sinv[t] = __builtin_amdgcn_rcpf(mx - mn);
    }
    if (t == 0) {
        double s = 0.0, s2 = 0.0;
        for (int i = 0; i < SLOTS; i++) { s += sums[2 * i]; s2 += sums[2 * i + 1]; }
        double M = (double)C_CH * NP;
        double mean = s / M;
        double var = (s2 - s * s / M) / (M - 1.0);
        sstat[0] = (float)mean;
        sstat[1] = (float)(0.1 / sqrt(var));
    }
    __syncthreads();

    const float INV_DENOM = 1.0f / (1.0f / 19.0f + 1e-7f);
    float mean = sstat[0], escale = sstat[1];
    size_t tbase = (size_t)blockIdx.x * (C_CH * 32);
    int n0 = blockIdx.x * 32;

    #pragma unroll
    for (int i = 0; i < 16; i++) {
        int idx = i * 256 + t;       // idx = c*32 + j  (contiguous tile read)
        int c = idx >> 5;
        int j = idx & 31;
        float x = xtile[tbase + idx];
        float e = etile[tbase + idx];
        float xn = (x - smin[c]) * sinv[c];
        int seg = (int)floorf(xn * 19.0f);
        seg = max(0, min(18, seg));
        float y0 = syp[c * K_PWL + seg];
        float y1 = syp[c * K_PWL + seg + 1];
        float y = fmaf((xn - (float)seg * (1.0f / 19.0f)) * INV_DENOM, y1 - y0, y0);
        y = fmaf(e - mean, escale, y);
        ytile[c * 33 + j] = y;
    }
    __syncthreads();
    #pragma unroll
    for (int i = 0; i < 16; i++) {
        int idx = i * 256 + t;
        int j = idx >> 7;
        int c = idx & 127;
        out[(size_t)(n0 + j) * C_CH + c] = ytile[c * 33 + j];
    }
}

extern "C" void kernel_launch(void* const* d_in, const int* in_sizes, int n_in,
                              void* d_out, int out_size, void* d_ws, size_t ws_size,
                              hipStream_t stream) {
    const float* zf  = (const float*)d_in[0];
    const float* zx  = (const float*)d_in[1];
    const float* ze  = (const float*)d_in[2];
    const float* Wx1 = (const float*)d_in[3];
    const float* bx1 = (const float*)d_in[4];
    const float* Wx2 = (const float*)d_in[5];
    const float* bx2 = (const float*)d_in[6];
    const float* We1 = (const float*)d_in[7];
    const float* be1 = (const float*)d_in[8];
    const float* We2 = (const float*)d_in[9];
    const float* be2 = (const float*)d_in[10];
    const float* Wf1 = (const float*)d_in[11];
    const float* bf1 = (const float*)d_in[12];
    const float* Wf2 = (const float*)d_in[13];
    const float* bf2 = (const float*)d_in[14];
    const unsigned char* dirs = (const unsigned char*)d_in[15];

    float* xtile = (float*)d_ws;                        // [NP/32][C][32]
    float* etile = xtile + (size_t)C_CH * NP;           // [NP/32][C][32]
    float* ypw   = etile + (size_t)C_CH * NP;
    unsigned* cminE = (unsigned*)(ypw + C_CH * K_PWL);
    unsigned* cmaxE = cminE + C_CH;
    double* sums = (double*)(cmaxE + C_CH);   // byte offset is 8-aligned

    hipLaunchKernelGGL(prep, dim3(1), dim3(256), 0, stream,
                       zf, Wf1, bf1, Wf2, bf2, dirs, ypw, cminE, cmaxE, sums);
    hipLaunchKernelGGL(pass1t, dim3(NP / (256 * P1PTS), C_CH), dim3(256), 0, stream,
                       zx, ze, Wx1, bx1, Wx2, bx2, We1, be1, We2, be2,
                       xtile, etile, cminE, cmaxE, sums);
    hipLaunchKernelGGL(pass2t, dim3(NP / 32), dim3(256), 0, stream,
                       xtile, etile, ypw, cminE, cmaxE, sums, (float*)d_out);
}